// Round 12
// baseline (48.113 us; speedup 1.0000x reference)
//
#include <hip/hip_runtime.h>

#define BB 8
#define CC 384
#define HH 64
#define WW 64
#define NH 6
#define HD 64
#define PLANE (HH*WW)        /* 4096 */
#define QKSCALE 0.125f
#define CH_B  (PLANE*4)      /* 16384 bytes per channel step */
#define CHUNK_B (8*CH_B)     /* 131072 bytes per 8-channel chunk */
#define NCHUNK_QK 8          /* full 64 channels: QK duplicated per h-wave */
#define NCHUNK_PV 4          /* 32-channel half per wave */

typedef float f32x4 __attribute__((ext_vector_type(4)));
typedef int   i32x4 __attribute__((ext_vector_type(4)));

__device__ __forceinline__ i32x4 make_srsrc(const void* p) {
  union { unsigned long long a; int w[2]; } u; u.a = (unsigned long long)p;
  i32x4 r; r.x = u.w[0]; r.y = u.w[1]; r.z = -1 /*num_records: disable*/; r.w = 0x00020000;
  return r;
}

// buffer_load_dword: dst <- rsrc[voff + soff]; counted by vmcnt, issue order pinned.
__device__ __forceinline__ void bl(float& dst, i32x4 rsrc, int voff, int soff) {
  asm volatile("buffer_load_dword %0, %1, %2, %3 offen"
               : "=v"(dst) : "v"(voff), "s"(rsrc), "s"(soff));
}

__device__ __forceinline__ void issue_q8(float (&qb)[8], i32x4 rq, int voq) {
#pragma unroll
  for (int dd = 0; dd < 8; ++dd) bl(qb[dd], rq, voq, dd * CH_B);
}
__device__ __forceinline__ void issue_r24(float (&kb)[24], i32x4 rk, int vo0, int vo1, int vo2) {
#pragma unroll
  for (int dd = 0; dd < 8; ++dd) bl(kb[0 * 8 + dd], rk, vo0, dd * CH_B);
#pragma unroll
  for (int dd = 0; dd < 8; ++dd) bl(kb[1 * 8 + dd], rk, vo1, dd * CH_B);
#pragma unroll
  for (int dd = 0; dd < 8; ++dd) bl(kb[2 * 8 + dd], rk, vo2, dd * CH_B);
}

__global__ __launch_bounds__(256, 4) void dilate_attn_kernel(
    const float* __restrict__ qg, const float* __restrict__ kg,
    const float* __restrict__ vg, float* __restrict__ outg) {
  // bijective XCD swizzle: 1536 blocks, 192 per XCD, consecutive y-strips per XCD
  const int blk  = (blockIdx.x % 8) * 192 + (blockIdx.x / 8);
  const int y0   = (blk % 32) * 2;     // 2 y-rows per block
  const int bh   = blk / 32;           // b*NH + head
  const int head = bh % NH;
  const int b    = bh / NH;
  const int lane = threadIdx.x & 63;   // x
  const int w    = threadIdx.x >> 6;   // 0..3
  const int yloc = w >> 1;             // 0/1: which y-row
  const int h    = w & 1;              // 0/1: which d-half for PV (32 channels)
  const int y = y0 + yloc;
  const int x = lane;

  const int laneL = (lane - 1) & 63;   // srcLane for x-1 (wraps onto masked zeros)
  const int laneR = (lane + 1) & 63;   // srcLane for x+1

  const i32x4 rq = make_srsrc(qg);
  const i32x4 rk = make_srsrc(kg);
  const i32x4 rv = make_srsrc(vg);

  // byte base of this head's slab (FULL range for q/k; h-offset applied to v only)
  const int slab4 = (b * CC + head * HD) * (PLANE * 4);
  const int voq = slab4 + (y * WW + x) * 4;

  int vor[3];   // per-row byte offsets for k (full range)
  float m[9];
#pragma unroll
  for (int r = 0; r < 3; ++r) {
    const int yy = y + r - 1;
    const int yc = min(max(yy, 0), HH - 1);
    vor[r] = slab4 + (yc * WW + x) * 4;
    const bool rowok = (yy >= 0) && (yy < HH);
#pragma unroll
    for (int dx = 0; dx < 3; ++dx) {
      const int xx = x + dx - 1;
      m[r * 3 + dx] = (rowok && xx >= 0 && xx < WW) ? 1.0f : 0.0f;
    }
  }

  // ---- QK^T over ALL 64 channels (duplicated between the two h-waves of a
  // y-row; the twin wave's identical loads hit L1/L2, HBM traffic unchanged).
  // Byte-identical pipeline to the passing R8 kernel.
  float t[9];
#pragma unroll
  for (int i = 0; i < 9; ++i) t[i] = 0.0f;

  float qb[2][8], kb[2][24];
  issue_q8(qb[0], rq, voq);
  issue_r24(kb[0], rk, vor[0], vor[1], vor[2]);

#pragma unroll
  for (int c = 0; c < NCHUNK_QK; ++c) {
    const int cur = c & 1, nxt = cur ^ 1;
    if (c < NCHUNK_QK - 1) {
      issue_q8(qb[nxt], rq, voq + (c + 1) * CHUNK_B);
      issue_r24(kb[nxt], rk, vor[0] + (c + 1) * CHUNK_B,
                             vor[1] + (c + 1) * CHUNK_B,
                             vor[2] + (c + 1) * CHUNK_B);
    }
    // q(cur) ready: newer LOADS = k(cur)24 [+ q(nxt)8 + k(nxt)24]
    if (c < NCHUNK_QK - 1) { asm volatile("s_waitcnt vmcnt(56)" ::: "memory"); }
    else                   { asm volatile("s_waitcnt vmcnt(24)" ::: "memory"); }
    __builtin_amdgcn_sched_barrier(0);
    float qm[8], qp[8];
#pragma unroll
    for (int dd = 0; dd < 8; ++dd) {
      qm[dd] = __shfl(qb[cur][dd], laneL);  // q(x-1)
      qp[dd] = __shfl(qb[cur][dd], laneR);  // q(x+1)
    }
    // k(cur) ready: newer LOADS = [q(nxt)8 + k(nxt)24]
    if (c < NCHUNK_QK - 1) { asm volatile("s_waitcnt vmcnt(32)" ::: "memory"); }
    else                   { asm volatile("s_waitcnt vmcnt(0)"  ::: "memory"); }
    __builtin_amdgcn_sched_barrier(0);
#pragma unroll
    for (int dd = 0; dd < 8; ++dd) {
#pragma unroll
      for (int r = 0; r < 3; ++r) {
        const float kc = kb[cur][r * 8 + dd];
        t[r * 3 + 0] = fmaf(kc, qp[dd], t[r * 3 + 0]);       // dx=-1 uses q(x+1)
        t[r * 3 + 1] = fmaf(kc, qb[cur][dd], t[r * 3 + 1]);  // dx= 0
        t[r * 3 + 2] = fmaf(kc, qm[dd], t[r * 3 + 2]);       // dx=+1 uses q(x-1)
      }
    }
  }

  // ---- issue PV chunk 0 (this wave's v-half); flies under the softmax ----
  const int vv0 = vor[0] + h * 32 * CH_B;
  const int vv1 = vor[1] + h * 32 * CH_B;
  const int vv2 = vor[2] + h * 32 * CH_B;
  float vb[2][24];
  issue_r24(vb[0], rv, vv0, vv1, vv2);

  // gather scores: s[r,dx](x) = t[r,dx](x+dx), mask, scale
  float s[9];
#pragma unroll
  for (int i = 0; i < 9; ++i) {
    const int dx = (i % 3) - 1;
    s[i] = __shfl(t[i], (lane + dx) & 63) * m[i] * QKSCALE;
  }
  // softmax over 9 (masked entries exactly 0, matching zero-padded ref)
  float mx = s[0];
#pragma unroll
  for (int i = 1; i < 9; ++i) mx = fmaxf(mx, s[i]);
  float sum = 0.0f;
#pragma unroll
  for (int i = 0; i < 9; ++i) { s[i] = __expf(s[i] - mx); sum += s[i]; }
  const float inv = 1.0f / sum;
#pragma unroll
  for (int i = 0; i < 9; ++i) s[i] = s[i] * inv * m[i];  // fold v-pad mask into p

  // pre-shift p: P[r,dx](j) = p[r,dx](j - dx); wrap lands on masked zeros
  float P[9];
#pragma unroll
  for (int i = 0; i < 9; ++i) {
    const int dx = (i % 3) - 1;
    P[i] = __shfl(s[i], (lane - dx) & 63);
  }

  // ---- PV over this wave's 32 channels; compiler stores trickled per chunk ----
  float* outp = outg + ((long)((b * HH + y) * WW + x)) * CC + head * HD + h * 32;

#pragma unroll
  for (int c = 0; c < NCHUNK_PV; ++c) {
    const int cur = c & 1, nxt = cur ^ 1;
    if (c < NCHUNK_PV - 1)
      issue_r24(vb[nxt], rv, vv0 + (c + 1) * CHUNK_B,
                             vv1 + (c + 1) * CHUNK_B,
                             vv2 + (c + 1) * CHUNK_B);
    // v(cur) ready <=> <= 24 newer v(nxt) loads outstanding (loads-only count;
    // interleaved compiler stores only lengthen the wait -> safe)
    if (c < NCHUNK_PV - 1) { asm volatile("s_waitcnt vmcnt(24)" ::: "memory"); }
    else                   { asm volatile("s_waitcnt vmcnt(0)"  ::: "memory"); }
    __builtin_amdgcn_sched_barrier(0);

#pragma unroll
    for (int g = 0; g < 2; ++g) {
      f32x4 ov;
#pragma unroll
      for (int j = 0; j < 4; ++j) {
        const int dd = g * 4 + j;
        float cm = 0.f, cz = 0.f, cp = 0.f;
#pragma unroll
        for (int r = 0; r < 3; ++r) {
          const float vc = vb[cur][r * 8 + dd];
          cm = fmaf(P[r * 3 + 0], vc, cm);
          cz = fmaf(P[r * 3 + 1], vc, cz);
          cp = fmaf(P[r * 3 + 2], vc, cp);
        }
        ov[j] = cz + __shfl(cm, laneL) + __shfl(cp, laneR);
      }
      *reinterpret_cast<f32x4*>(outp + c * 8 + g * 4) = ov;
    }
  }
}

extern "C" void kernel_launch(void* const* d_in, const int* in_sizes, int n_in,
                              void* d_out, int out_size, void* d_ws, size_t ws_size,
                              hipStream_t stream) {
  const float* q = (const float*)d_in[0];
  const float* k = (const float*)d_in[1];
  const float* v = (const float*)d_in[2];
  float* out = (float*)d_out;
  const int blocks = BB * NH * (HH / 2);  // 1536: (b,head) x 32 y-pairs
  dilate_attn_kernel<<<blocks, 256, 0, stream>>>(q, k, v, out);
}

// Round 13
// 43.301 us; speedup vs baseline: 1.1111x; 1.1111x over previous
//
#include <hip/hip_runtime.h>

#define BB 8
#define CC 384
#define HH 64
#define WW 64
#define NH 6
#define HD 64
#define PLANE (HH*WW)        /* 4096 */
#define QKSCALE 0.125f
#define CH_B  (PLANE*4)      /* 16384 bytes per channel step */

typedef float f32x4 __attribute__((ext_vector_type(4)));
typedef int   i32x4 __attribute__((ext_vector_type(4)));

__device__ __forceinline__ i32x4 make_srsrc(const void* p) {
  union { unsigned long long a; int w[2]; } u; u.a = (unsigned long long)p;
  i32x4 r; r.x = u.w[0]; r.y = u.w[1]; r.z = -1 /*num_records: disable*/; r.w = 0x00020000;
  return r;
}

// buffer_load_dwordx4: 16B per lane; counted by vmcnt, issue order pinned by volatile.
__device__ __forceinline__ void blx4(f32x4& dst, i32x4 rsrc, int voff, int soff) {
  asm volatile("buffer_load_dwordx4 %0, %1, %2, %3 offen"
               : "=v"(dst) : "v"(voff), "s"(rsrc), "s"(soff));
}

__global__ __launch_bounds__(256, 3) void dilate_attn_kernel(
    const float* __restrict__ qg, const float* __restrict__ kg,
    const float* __restrict__ vg, float* __restrict__ outg) {
  // bijective XCD swizzle: 768 blocks, 96 per XCD
  const int blk  = (blockIdx.x % 8) * 96 + (blockIdx.x / 8);
  const int y0   = (blk % 16) * 4;
  const int bh   = blk / 16;           // b*NH + head
  const int head = bh % NH;
  const int b    = bh / NH;
  const int lane = threadIdx.x & 63;
  const int warp = threadIdx.x >> 6;
  const int y = y0 + warp;
  const int g = lane >> 4;             // channel subgroup 0..3
  const int u = lane & 15;             // x-quad index: pixels 4u..4u+3

  const int laneM = (lane & 48) | ((u + 15) & 15);  // quad u-1 (halo x-1)
  const int laneP = (lane & 48) | ((u + 1) & 15);   // quad u+1 (halo x+4)

  const i32x4 rq = make_srsrc(qg);
  const i32x4 rk = make_srsrc(kg);
  const i32x4 rv = make_srsrc(vg);

  // per-lane byte base: head slab + this lane's channel-subgroup + pixel quad
  const int slab4 = (b * CC + head * HD) * (PLANE * 4) + g * CH_B;
  const int voq = slab4 + (y * WW + 4 * u) * 4;

  int vok[3]; float rowm[3];
#pragma unroll
  for (int r = 0; r < 3; ++r) {
    const int yy = y + r - 1;
    const int yc = min(max(yy, 0), HH - 1);
    vok[r] = slab4 + (yc * WW + 4 * u) * 4;
    rowm[r] = (yy >= 0 && yy < HH) ? 1.0f : 0.0f;
  }
  const float eL = (u == 0)  ? 0.0f : 1.0f;   // x=0 lacks x-1 tap
  const float eR = (u == 15) ? 0.0f : 1.0f;   // x=63 lacks x+1 tap

  // ---- QK^T: t[r*3+(dx+1)][j] = sum_d q_d(x_j) * k_d(row r, x_j+dx) ----
  float t[9][4];
#pragma unroll
  for (int i = 0; i < 9; ++i)
#pragma unroll
    for (int j = 0; j < 4; ++j) t[i][j] = 0.0f;

  f32x4 qb[2][2], kb[2][6];
  // prologue: chunk 0 (channels 0..7)
  blx4(qb[0][0], rq, voq, 0 * CH_B);
  blx4(qb[0][1], rq, voq, 4 * CH_B);
#pragma unroll
  for (int r = 0; r < 3; ++r)
#pragma unroll
    for (int ci = 0; ci < 2; ++ci)
      blx4(kb[0][r * 2 + ci], rk, vok[r], (4 * ci) * CH_B);

#pragma unroll
  for (int c = 0; c < 8; ++c) {
    const int cur = c & 1, nxt = cur ^ 1;
    if (c < 7) {
      const int cb = (c + 1) * 8;
      blx4(qb[nxt][0], rq, voq, (cb + 0) * CH_B);
      blx4(qb[nxt][1], rq, voq, (cb + 4) * CH_B);
#pragma unroll
      for (int r = 0; r < 3; ++r)
#pragma unroll
        for (int ci = 0; ci < 2; ++ci)
          blx4(kb[nxt][r * 2 + ci], rk, vok[r], (cb + 4 * ci) * CH_B);
    }
    // chunk c ready: newer LOADS = chunk c+1's 8 (loads-only suffix -> safe)
    if (c < 7) { asm volatile("s_waitcnt vmcnt(8)" ::: "memory"); }
    else       { asm volatile("s_waitcnt vmcnt(0)" ::: "memory"); }
    __builtin_amdgcn_sched_barrier(0);

#pragma unroll
    for (int ci = 0; ci < 2; ++ci) {
      const f32x4 qv = qb[cur][ci];
#pragma unroll
      for (int r = 0; r < 3; ++r) {
        const f32x4 kv = kb[cur][r * 2 + ci];
        const float km1 = __shfl(kv[3], laneM);   // k(x-1 of quad)
        const float kp4 = __shfl(kv[0], laneP);   // k(x+4 of quad)
        // dx=-1: k at x_j-1
        t[r*3+0][0] = fmaf(qv[0], km1,  t[r*3+0][0]);
        t[r*3+0][1] = fmaf(qv[1], kv[0], t[r*3+0][1]);
        t[r*3+0][2] = fmaf(qv[2], kv[1], t[r*3+0][2]);
        t[r*3+0][3] = fmaf(qv[3], kv[2], t[r*3+0][3]);
        // dx=0
        t[r*3+1][0] = fmaf(qv[0], kv[0], t[r*3+1][0]);
        t[r*3+1][1] = fmaf(qv[1], kv[1], t[r*3+1][1]);
        t[r*3+1][2] = fmaf(qv[2], kv[2], t[r*3+1][2]);
        t[r*3+1][3] = fmaf(qv[3], kv[3], t[r*3+1][3]);
        // dx=+1: k at x_j+1
        t[r*3+2][0] = fmaf(qv[0], kv[1], t[r*3+2][0]);
        t[r*3+2][1] = fmaf(qv[1], kv[2], t[r*3+2][1]);
        t[r*3+2][2] = fmaf(qv[2], kv[3], t[r*3+2][2]);
        t[r*3+2][3] = fmaf(qv[3], kp4,  t[r*3+2][3]);
      }
    }
  }

  // ---- issue PV chunk 0: flies under the reduce + softmax ----
  f32x4 vb[2][6];
#pragma unroll
  for (int r = 0; r < 3; ++r)
#pragma unroll
    for (int ci = 0; ci < 2; ++ci)
      blx4(vb[0][r * 2 + ci], rv, vok[r], (4 * ci) * CH_B);

  // ---- butterfly reduce over channel subgroups (g): xor 16, xor 32 ----
#pragma unroll
  for (int i = 0; i < 9; ++i)
#pragma unroll
    for (int j = 0; j < 4; ++j) {
      t[i][j] += __shfl_xor(t[i][j], 16);
      t[i][j] += __shfl_xor(t[i][j], 32);
    }

  // ---- softmax per pixel j (masked entries exactly 0, matching zero-pad ref) ----
  float p[9][4];
#pragma unroll
  for (int j = 0; j < 4; ++j) {
    float sj[9];
#pragma unroll
    for (int r = 0; r < 3; ++r)
#pragma unroll
      for (int d = 0; d < 3; ++d)
        sj[r * 3 + d] = t[r * 3 + d][j] * rowm[r] * QKSCALE;
    if (j == 0) { sj[0] *= eL; sj[3] *= eL; sj[6] *= eL; }
    if (j == 3) { sj[2] *= eR; sj[5] *= eR; sj[8] *= eR; }
    float mx = sj[0];
#pragma unroll
    for (int i = 1; i < 9; ++i) mx = fmaxf(mx, sj[i]);
    float sum = 0.0f;
#pragma unroll
    for (int i = 0; i < 9; ++i) { sj[i] = __expf(sj[i] - mx); sum += sj[i]; }
    const float inv = 1.0f / sum;
#pragma unroll
    for (int r = 0; r < 3; ++r)
#pragma unroll
      for (int d = 0; d < 3; ++d)
        p[r * 3 + d][j] = sj[r * 3 + d] * inv * rowm[r];  // fold row mask into p
    if (j == 0) { p[0][0] *= eL; p[3][0] *= eL; p[6][0] *= eL; }
    if (j == 3) { p[2][3] *= eR; p[5][3] *= eR; p[8][3] *= eR; }
  }

  // ---- PV + per-wave LDS transpose (64x9 pad: 2-way banks = free) ----
  __shared__ float ldsT[4][576];
  float* ldsw = ldsT[warp];
  float* outp = outg + ((long)((b * HH + y) * WW + lane)) * CC + head * HD;

#pragma unroll
  for (int c = 0; c < 8; ++c) {
    const int cur = c & 1, nxt = cur ^ 1;
    if (c < 7) {
      const int cb = (c + 1) * 8;
#pragma unroll
      for (int r = 0; r < 3; ++r)
#pragma unroll
        for (int ci = 0; ci < 2; ++ci)
          blx4(vb[nxt][r * 2 + ci], rv, vok[r], (cb + 4 * ci) * CH_B);
    }
    // v(cur) ready: newer LOADS = 6 (compiler stores only lengthen wait -> safe)
    if (c < 7) { asm volatile("s_waitcnt vmcnt(6)" ::: "memory"); }
    else       { asm volatile("s_waitcnt vmcnt(0)" ::: "memory"); }
    __builtin_amdgcn_sched_barrier(0);

    float o[2][4];
#pragma unroll
    for (int ci = 0; ci < 2; ++ci)
#pragma unroll
      for (int j = 0; j < 4; ++j) o[ci][j] = 0.0f;

#pragma unroll
    for (int ci = 0; ci < 2; ++ci)
#pragma unroll
      for (int r = 0; r < 3; ++r) {
        const f32x4 vv = vb[cur][r * 2 + ci];
        const float vm1 = __shfl(vv[3], laneM);
        const float vp4 = __shfl(vv[0], laneP);
        o[ci][0] += p[r*3+0][0]*vm1  + p[r*3+1][0]*vv[0] + p[r*3+2][0]*vv[1];
        o[ci][1] += p[r*3+0][1]*vv[0] + p[r*3+1][1]*vv[1] + p[r*3+2][1]*vv[2];
        o[ci][2] += p[r*3+0][2]*vv[1] + p[r*3+1][2]*vv[2] + p[r*3+2][2]*vv[3];
        o[ci][3] += p[r*3+0][3]*vv[2] + p[r*3+1][3]*vv[3] + p[r*3+2][3]*vp4;
      }

    // transpose (g,u)-layout -> pixel layout through LDS (same-wave, in-order DS)
#pragma unroll
    for (int ci = 0; ci < 2; ++ci)
#pragma unroll
      for (int j = 0; j < 4; ++j)
        ldsw[(4 * u + j) * 9 + 4 * ci + g] = o[ci][j];

    f32x4 o0, o1;
#pragma unroll
    for (int c2 = 0; c2 < 4; ++c2) {
      o0[c2] = ldsw[lane * 9 + c2];
      o1[c2] = ldsw[lane * 9 + 4 + c2];
    }
    *reinterpret_cast<f32x4*>(outp + c * 8)     = o0;
    *reinterpret_cast<f32x4*>(outp + c * 8 + 4) = o1;
  }
}

extern "C" void kernel_launch(void* const* d_in, const int* in_sizes, int n_in,
                              void* d_out, int out_size, void* d_ws, size_t ws_size,
                              hipStream_t stream) {
  const float* q = (const float*)d_in[0];
  const float* k = (const float*)d_in[1];
  const float* v = (const float*)d_in[2];
  float* out = (float*)d_out;
  const int blocks = BB * NH * (HH / 4);  // 768
  dilate_attn_kernel<<<blocks, 256, 0, stream>>>(q, k, v, out);
}